// Round 8
// baseline (87.551 us; speedup 1.0000x reference)
//
#include <hip/hip_runtime.h>
#include <math.h>

#define B_   8
#define L_   4
#define P_   1024
#define C_   256
#define NH_  8
#define NS_  4
#define HD_  32

typedef _Float16 half8 __attribute__((ext_vector_type(8)));
typedef float    f32x4 __attribute__((ext_vector_type(4)));

// ws layout (float offsets)
#define G_F     0u          // projected maps fp16 (l,b,s,32): 1,392,640 halves
#define WU_F    5586944u    // WuT fp16 (96,256) -> 12288 float slots
#define BU_F    5611520u    // unified bias (96)

__constant__ const int kGoff[4] = {0, 1048576, 1310720, 1376256};  // half units

// ---------------------------------------------------------------------------
// prep: gproj (bx<85) + weight unify/convert (bx==85, by==0).
// gproj: g(b,s,:) = feat(b,:,s) @ E_l, fp16 out.
// ---------------------------------------------------------------------------
__global__ __launch_bounds__(256) void prep(
    const float* __restrict__ f0, const float* __restrict__ f1,
    const float* __restrict__ f2, const float* __restrict__ f3,
    const float* __restrict__ embed_w, _Float16* __restrict__ g16,
    const float* __restrict__ wa, const float* __restrict__ ba,
    const float* __restrict__ wo, const float* __restrict__ bo,
    _Float16* __restrict__ WuT, float* __restrict__ bu) {
  __shared__ float eL[C_ * HD_];   // 32 KB
  __shared__ float fl[32][64];     // 8 KB
  const int t = threadIdx.x;
  const int b = blockIdx.y;
  int bx = blockIdx.x, l, tile;

  if (bx == 85) {                  // ---- weight conversion block ----
    if (b != 0) return;
    #pragma unroll 4
    for (int i = 0; i < 32; ++i) {           // wa (256,32): 8192 elems
      const int a = i * 256 + t;
      WuT[(a & 31) * 256 + (a >> 5)] = (_Float16)wa[a];
    }
    #pragma unroll 4
    for (int i = 0; i < 64; ++i) {           // wo (256,64): 16384 elems
      const int a = i * 256 + t;
      WuT[(32 + (a & 63)) * 256 + (a >> 6)] = (_Float16)wo[a];
    }
    if (t < 96) bu[t] = (t < 32) ? ba[t] : bo[t - 32];
    return;
  }

  const float* src;
  if (bx < 64)      { l = 0; tile = bx;      src = f0; }
  else if (bx < 80) { l = 1; tile = bx - 64; src = f1; }
  else if (bx < 84) { l = 2; tile = bx - 80; src = f2; }
  else              { l = 3; tile = 0;       src = f3; }
  const int Wl = 64 >> l, S = Wl * Wl;
  const int s0 = tile * 64;

  const float* E = embed_w + (size_t)l * (C_ * HD_);
  #pragma unroll
  for (int q = 0; q < 32; ++q) eL[q * 256 + t] = E[q * 256 + t];

  const float* sb = src + (size_t)b * C_ * S + s0;
  const int sl = t & 63, dg = t >> 6;
  float acc[8];
  #pragma unroll
  for (int e = 0; e < 8; ++e) acc[e] = 0.f;

  for (int c0 = 0; c0 < 256; c0 += 32) {
    __syncthreads();
    #pragma unroll
    for (int q = 0; q < 8; ++q) {
      const int e = q * 256 + t;
      fl[e >> 6][e & 63] = sb[(size_t)(c0 + (e >> 6)) * S + (e & 63)];
    }
    __syncthreads();
    #pragma unroll 8
    for (int ci = 0; ci < 32; ++ci) {
      const float f = fl[ci][sl];
      const float4* ep = (const float4*)&eL[(c0 + ci) * 32 + dg * 8];
      const float4 e0 = ep[0], e1 = ep[1];
      acc[0] += f * e0.x; acc[1] += f * e0.y; acc[2] += f * e0.z; acc[3] += f * e0.w;
      acc[4] += f * e1.x; acc[5] += f * e1.y; acc[6] += f * e1.z; acc[7] += f * e1.w;
    }
  }
  _Float16* gd = g16 + kGoff[l] + ((size_t)b * S + s0 + sl) * 32 + dg * 8;
  const half8 hv = {(_Float16)acc[0], (_Float16)acc[1], (_Float16)acc[2], (_Float16)acc[3],
                    (_Float16)acc[4], (_Float16)acc[5], (_Float16)acc[6], (_Float16)acc[7]};
  *(half8*)gd = hv;
}

// ---------------------------------------------------------------------------
// k23_main: fused logits GEMM (MFMA fp16) + softmax/tanh -> samp in LDS ->
// bilinear gather of fp16 projected maps -> out. 64 points/block, 512 blocks.
// ---------------------------------------------------------------------------
#define XH  136         // padded half stride (272 B = 17*16 B)
#define LGS 100         // logits row stride (floats)
// samp LDS: float4 slot = pp*33 + s*8 + h  (pp<64, s<4, h<8), max 2110
__global__ __launch_bounds__(256) void k23_main(
    const float*    __restrict__ x,     // (32768, 256)
    const float*    __restrict__ ref,   // (32768, 2)
    const _Float16* __restrict__ WuT,   // (96, 256) K-major
    const float*    __restrict__ bu,    // (96)
    const _Float16* __restrict__ g16,   // projected maps fp16
    const float*    __restrict__ embed_b, // (L, 32)
    float*          __restrict__ out)   // (32768, 256)
{
  __shared__ float4 smraw4[3711];       // 59376 B
  _Float16* smx  = (_Float16*)smraw4;            // [64][XH]
  _Float16* smw  = (_Float16*)smraw4 + 64 * XH;  // [96][XH]
  float*    lg   = (float*)smraw4;               // [64][LGS] (reuse after GEMM)
  float4*   samp = smraw4 + 1600;                // offset 25600 B

  const int t = threadIdx.x, blk = blockIdx.x;   // 512 blocks
  const int lane = t & 63, w = t >> 6;
  const int lr = lane & 15, kg = lane >> 4;
  const int gp0 = blk * 64;
  const int l  = (gp0 >> 10) & 3;
  const int bb = gp0 >> 12;
  const int Wl = 64 >> l;
  const int gbase = kGoff[l] + bb * Wl * Wl * 32;   // half units

  // ---- phase 1: MFMA GEMM (fp16 in, fp32 acc) ----
  f32x4 acc[6];
  #pragma unroll
  for (int nt = 0; nt < 6; ++nt) acc[nt] = (f32x4){0.f, 0.f, 0.f, 0.f};

  #pragma unroll
  for (int chunk = 0; chunk < 2; ++chunk) {
    const int c0 = chunk * 128;
    if (chunk) __syncthreads();
    {
      const int pt = t >> 2, q = t & 3;
      const float4* src = (const float4*)(x + (size_t)(gp0 + pt) * 256 + c0 + q * 32);
      _Float16* dst = smx + pt * XH + q * 32;
      #pragma unroll
      for (int i = 0; i < 4; ++i) {
        const float4 v0 = src[2 * i], v1 = src[2 * i + 1];
        half8 h = {(_Float16)v0.x, (_Float16)v0.y, (_Float16)v0.z, (_Float16)v0.w,
                   (_Float16)v1.x, (_Float16)v1.y, (_Float16)v1.z, (_Float16)v1.w};
        *(half8*)(dst + i * 8) = h;
      }
    }
    if (t < 192) {
      const int n = t >> 1, ho = (t & 1) * 64;
      const float4* src = (const float4*)(WuT + (size_t)n * 256 + c0 + ho);
      float4* dst = (float4*)(smw + n * XH + ho);
      #pragma unroll
      for (int i = 0; i < 8; ++i) dst[i] = src[i];
    }
    __syncthreads();

    #pragma unroll
    for (int ks = 0; ks < 4; ++ks) {
      const half8 a = *(const half8*)(smx + (w * 16 + lr) * XH + ks * 32 + kg * 8);
      #pragma unroll
      for (int nt = 0; nt < 6; ++nt) {
        const half8 bf = *(const half8*)(smw + (nt * 16 + lr) * XH + ks * 32 + kg * 8);
        acc[nt] = __builtin_amdgcn_mfma_f32_16x16x32_f16(a, bf, acc[nt], 0, 0, 0);
      }
    }
  }
  __syncthreads();

  // ---- spill logits (+bias) ----
  #pragma unroll
  for (int nt = 0; nt < 6; ++nt) {
    const int n = nt * 16 + lr;
    const float bv = bu[n];
    #pragma unroll
    for (int r = 0; r < 4; ++r)
      lg[(w * 16 + kg * 4 + r) * LGS + n] = acc[nt][r] + bv;
  }
  __syncthreads();

  // ---- phase 2: softmax + tanh + grid mapping -> samp LDS ----
  #pragma unroll
  for (int k = 0; k < 8; ++k) {
    const int slot = k * 256 + t;
    const int pp = slot >> 5, j = slot & 31;
    const int gp = gp0 + pp;
    const float* lgp = lg + pp * LGS;
    const int h4 = (j >> 2) * 4;
    const float l0 = lgp[h4], l1 = lgp[h4 + 1], l2 = lgp[h4 + 2], l3 = lgp[h4 + 3];
    const float m = fmaxf(fmaxf(l0, l1), fmaxf(l2, l3));
    const float e0 = expf(l0 - m), e1 = expf(l1 - m), e2 = expf(l2 - m), e3 = expf(l3 - m);
    const float inv = 1.f / (e0 + e1 + e2 + e3);
    const float es[4] = {e0, e1, e2, e3};
    const float wj = es[j & 3] * inv;
    const float ox = tanhf(lgp[32 + 2 * j])     + ref[(size_t)gp * 2];
    const float oy = tanhf(lgp[32 + 2 * j + 1]) + ref[(size_t)gp * 2 + 1];
    const float sc = 0.5f * (float)(Wl - 1);
    samp[pp * 33 + (j & 3) * 8 + (j >> 2)] =
        make_float4(wj, (ox + 1.f) * sc, (oy + 1.f) * sc, 0.f);
  }
  __syncthreads();

  // ---- phase 3: bilinear gather + weighted sum ----
  const int dq = t & 3, h8 = (t >> 2) & 7, ptl = t >> 5;
  float bias[8];
  {
    const float4* be = (const float4*)(embed_b + l * 32 + dq * 8);
    const float4 b0 = be[0], b1 = be[1];
    bias[0] = b0.x; bias[1] = b0.y; bias[2] = b0.z; bias[3] = b0.w;
    bias[4] = b1.x; bias[5] = b1.y; bias[6] = b1.z; bias[7] = b1.w;
  }
  #pragma unroll
  for (int ptq = 0; ptq < 8; ++ptq) {
    const int pp = ptq * 8 + ptl;
    float a[8];
    #pragma unroll
    for (int j = 0; j < 8; ++j) a[j] = bias[j];
    #pragma unroll
    for (int s = 0; s < 4; ++s) {
      const float4 sm = samp[pp * 33 + s * 8 + h8];
      const float fx = sm.y, fy = sm.z;
      const float x0f = floorf(fx), y0f = floorf(fy);
      const int x0 = (int)x0f, y0 = (int)y0f, x1 = x0 + 1, y1 = y0 + 1;
      const float wx1 = fx - x0f, wy1 = fy - y0f;
      const float wx0 = 1.f - wx1, wy0 = 1.f - wy1;
      const float xv0 = (x0 >= 0 && x0 < Wl) ? 1.f : 0.f;
      const float xv1 = (x1 >= 0 && x1 < Wl) ? 1.f : 0.f;
      const float yv0 = (y0 >= 0 && y0 < Wl) ? 1.f : 0.f;
      const float yv1 = (y1 >= 0 && y1 < Wl) ? 1.f : 0.f;
      const int x0c = min(max(x0, 0), Wl - 1), x1c = min(max(x1, 0), Wl - 1);
      const int y0c = min(max(y0, 0), Wl - 1), y1c = min(max(y1, 0), Wl - 1);
      const float wv = sm.x;
      const float w00 = wv * wy0 * wx0 * yv0 * xv0;
      const float w01 = wv * wy0 * wx1 * yv0 * xv1;
      const float w10 = wv * wy1 * wx0 * yv1 * xv0;
      const float w11 = wv * wy1 * wx1 * yv1 * xv1;
      const int o00 = gbase + (y0c * Wl + x0c) * 32 + dq * 8;
      const int o01 = gbase + (y0c * Wl + x1c) * 32 + dq * 8;
      const int o10 = gbase + (y1c * Wl + x0c) * 32 + dq * 8;
      const int o11 = gbase + (y1c * Wl + x1c) * 32 + dq * 8;
      const half8 v00 = *(const half8*)(g16 + o00);
      const half8 v01 = *(const half8*)(g16 + o01);
      const half8 v10 = *(const half8*)(g16 + o10);
      const half8 v11 = *(const half8*)(g16 + o11);
      #pragma unroll
      for (int j = 0; j < 8; ++j)
        a[j] += w00 * (float)v00[j] + w01 * (float)v01[j]
              + w10 * (float)v10[j] + w11 * (float)v11[j];
    }
    float* od = out + (size_t)(gp0 + pp) * 256 + h8 * 32 + dq * 8;
    ((float4*)od)[0] = make_float4(a[0], a[1], a[2], a[3]);
    ((float4*)od)[1] = make_float4(a[4], a[5], a[6], a[7]);
  }
}

// ---------------------------------------------------------------------------
extern "C" void kernel_launch(void* const* d_in, const int* in_sizes, int n_in,
                              void* d_out, int out_size, void* d_ws, size_t ws_size,
                              hipStream_t stream) {
  const float* x      = (const float*)d_in[0];
  const float* ref    = (const float*)d_in[1];
  const float* w_attn = (const float*)d_in[6];
  const float* b_attn = (const float*)d_in[7];
  const float* w_off  = (const float*)d_in[8];
  const float* b_off  = (const float*)d_in[9];
  const float* emb_w  = (const float*)d_in[10];
  const float* emb_b  = (const float*)d_in[11];
  float* ws  = (float*)d_ws;
  float* out = (float*)d_out;

  _Float16* WuT = (_Float16*)(ws + WU_F);
  float*    bu  = ws + BU_F;
  _Float16* g16 = (_Float16*)(ws + G_F);

  prep<<<dim3(86, B_), 256, 0, stream>>>(
      (const float*)d_in[2], (const float*)d_in[3],
      (const float*)d_in[4], (const float*)d_in[5], emb_w, g16,
      w_attn, b_attn, w_off, b_off, WuT, bu);

  k23_main<<<B_ * L_ * P_ / 64, 256, 0, stream>>>(
      x, ref, WuT, bu, g16, emb_b, out);
}

// Round 9
// 58.894 us; speedup vs baseline: 1.4866x; 1.4866x over previous
//
#include <hip/hip_runtime.h>
#include <math.h>

#define B_   8
#define L_   4
#define P_   1024
#define C_   256
#define NH_  8
#define NS_  4
#define HD_  32

typedef _Float16 half8 __attribute__((ext_vector_type(8)));
typedef float    f32x4 __attribute__((ext_vector_type(4)));

// ws layout (float offsets)
#define G_F     0u          // projected maps fp16 (l,b,s,32): 2,785,280 halves
#define SAMP_F  1392640u    // per-sample (w,fx,fy,0) float4: 32768*32*4 floats

__constant__ const int kGoff[4] = {0, 1048576, 1310720, 1376256};  // half units

#define XH  136             // padded half stride (272 B = 17*16 B)
#define LGS 100             // logits row stride (floats)
#define NG_GPROJ 680        // 8 batches * 85 tiles

// ---------------------------------------------------------------------------
// stage1: horizontal fusion.
//   blocks [0, 680):   gproj  g(b,s,:) = feat(b,:,s) @ E_l  -> fp16
//   blocks [680,1192): k2     MFMA logits GEMM + softmax/tanh -> samp4
// ---------------------------------------------------------------------------
__global__ __launch_bounds__(256) void stage1(
    const float* __restrict__ f0, const float* __restrict__ f1,
    const float* __restrict__ f2, const float* __restrict__ f3,
    const float* __restrict__ embed_w, _Float16* __restrict__ g16,
    const float* __restrict__ x,    // (32768, 256)
    const float* __restrict__ ref,  // (32768, 2)
    const float* __restrict__ wa, const float* __restrict__ ba,
    const float* __restrict__ wo, const float* __restrict__ bo,
    float4* __restrict__ samp4)     // (32768, 32)
{
  __shared__ float4 smraw4[2720];   // 43520 B shared by both paths
  const int t = threadIdx.x;
  const int bx = blockIdx.x;

  if (bx < NG_GPROJ) {
    // ================= gproj path =================
    float* eL = (float*)smraw4;            // [256*32] = 32 KB
    float (*fl)[64] = (float(*)[64])(eL + C_ * HD_);  // [32][64] = 8 KB
    const int b = bx / 85;
    int sub = bx - b * 85, l, tile;
    const float* src;
    if (sub < 64)      { l = 0; tile = sub;      src = f0; }
    else if (sub < 80) { l = 1; tile = sub - 64; src = f1; }
    else if (sub < 84) { l = 2; tile = sub - 80; src = f2; }
    else               { l = 3; tile = 0;        src = f3; }
    const int Wl = 64 >> l, S = Wl * Wl;
    const int s0 = tile * 64;

    const float* E = embed_w + (size_t)l * (C_ * HD_);
    #pragma unroll
    for (int q = 0; q < 32; ++q) eL[q * 256 + t] = E[q * 256 + t];

    const float* sb = src + (size_t)b * C_ * S + s0;
    const int sl = t & 63, dg = t >> 6;
    float acc[8];
    #pragma unroll
    for (int e = 0; e < 8; ++e) acc[e] = 0.f;

    for (int c0 = 0; c0 < 256; c0 += 32) {
      __syncthreads();
      #pragma unroll
      for (int q = 0; q < 8; ++q) {
        const int e = q * 256 + t;
        fl[e >> 6][e & 63] = sb[(size_t)(c0 + (e >> 6)) * S + (e & 63)];
      }
      __syncthreads();
      #pragma unroll 8
      for (int ci = 0; ci < 32; ++ci) {
        const float f = fl[ci][sl];
        const float4* ep = (const float4*)&eL[(c0 + ci) * 32 + dg * 8];
        const float4 e0 = ep[0], e1 = ep[1];
        acc[0] += f * e0.x; acc[1] += f * e0.y; acc[2] += f * e0.z; acc[3] += f * e0.w;
        acc[4] += f * e1.x; acc[5] += f * e1.y; acc[6] += f * e1.z; acc[7] += f * e1.w;
      }
    }
    _Float16* gd = g16 + kGoff[l] + ((size_t)b * S + s0 + sl) * 32 + dg * 8;
    const half8 hv = {(_Float16)acc[0], (_Float16)acc[1], (_Float16)acc[2], (_Float16)acc[3],
                      (_Float16)acc[4], (_Float16)acc[5], (_Float16)acc[6], (_Float16)acc[7]};
    *(half8*)gd = hv;
    return;
  }

  // ================= k2 path =================
  _Float16* smx = (_Float16*)smraw4;            // [64][XH]
  _Float16* smw = (_Float16*)smraw4 + 64 * XH;  // [96][XH]
  float*    lg  = (float*)smraw4;               // [64][LGS] (reuse after GEMM)

  const int blk = bx - NG_GPROJ;                // 0..511
  const int lane = t & 63, w = t >> 6;
  const int lr = lane & 15, kg = lane >> 4;
  const int gp0 = blk * 64;

  f32x4 acc[6];
  #pragma unroll
  for (int nt = 0; nt < 6; ++nt) acc[nt] = (f32x4){0.f, 0.f, 0.f, 0.f};

  #pragma unroll
  for (int chunk = 0; chunk < 2; ++chunk) {
    const int c0 = chunk * 128;
    if (chunk) __syncthreads();
    // stage x rows (fp32 -> fp16)
    {
      const int pt = t >> 2, q = t & 3;
      const float4* src = (const float4*)(x + (size_t)(gp0 + pt) * 256 + c0 + q * 32);
      _Float16* dst = smx + pt * XH + q * 32;
      #pragma unroll
      for (int i = 0; i < 4; ++i) {
        const float4 v0 = src[2 * i], v1 = src[2 * i + 1];
        half8 h = {(_Float16)v0.x, (_Float16)v0.y, (_Float16)v0.z, (_Float16)v0.w,
                   (_Float16)v1.x, (_Float16)v1.y, (_Float16)v1.z, (_Float16)v1.w};
        *(half8*)(dst + i * 8) = h;
      }
    }
    // stage weights: transpose-convert wa (c,32) / wo (c,64) -> smw[n][cc]
    {
      const float4* wa4 = (const float4*)(wa + c0 * 32);
      #pragma unroll
      for (int q = 0; q < 4; ++q) {
        const int la = (q * 256 + t) * 4;      // 0..4092
        const float4 v = wa4[q * 256 + t];
        const int cc = la >> 5, n = la & 31;
        smw[(n + 0) * XH + cc] = (_Float16)v.x;
        smw[(n + 1) * XH + cc] = (_Float16)v.y;
        smw[(n + 2) * XH + cc] = (_Float16)v.z;
        smw[(n + 3) * XH + cc] = (_Float16)v.w;
      }
      const float4* wo4 = (const float4*)(wo + c0 * 64);
      #pragma unroll
      for (int q = 0; q < 8; ++q) {
        const int la = (q * 256 + t) * 4;      // 0..8188
        const float4 v = wo4[q * 256 + t];
        const int cc = la >> 6, n = 32 + (la & 63);
        smw[(n + 0) * XH + cc] = (_Float16)v.x;
        smw[(n + 1) * XH + cc] = (_Float16)v.y;
        smw[(n + 2) * XH + cc] = (_Float16)v.z;
        smw[(n + 3) * XH + cc] = (_Float16)v.w;
      }
    }
    __syncthreads();

    #pragma unroll
    for (int ks = 0; ks < 4; ++ks) {
      const half8 a = *(const half8*)(smx + (w * 16 + lr) * XH + ks * 32 + kg * 8);
      #pragma unroll
      for (int nt = 0; nt < 6; ++nt) {
        const half8 bf = *(const half8*)(smw + (nt * 16 + lr) * XH + ks * 32 + kg * 8);
        acc[nt] = __builtin_amdgcn_mfma_f32_16x16x32_f16(a, bf, acc[nt], 0, 0, 0);
      }
    }
  }
  __syncthreads();

  // spill logits (+bias): D col = lane&15 (n), row = kg*4+r (point)
  #pragma unroll
  for (int nt = 0; nt < 6; ++nt) {
    const int n = nt * 16 + lr;
    const float bv = (n < 32) ? ba[n] : bo[n - 32];
    #pragma unroll
    for (int r = 0; r < 4; ++r)
      lg[(w * 16 + kg * 4 + r) * LGS + n] = acc[nt][r] + bv;
  }
  __syncthreads();

  // softmax + tanh + grid mapping -> samp4 (global)
  #pragma unroll
  for (int k = 0; k < 8; ++k) {
    const int slot = k * 256 + t;
    const int pp = slot >> 5, j = slot & 31;
    const int gp = gp0 + pp;
    const int l = (gp >> 10) & 3;
    const int Wl = 64 >> l;
    const float* lgp = lg + pp * LGS;
    const int h4 = (j >> 2) * 4;
    const float l0 = lgp[h4], l1 = lgp[h4 + 1], l2 = lgp[h4 + 2], l3 = lgp[h4 + 3];
    const float m = fmaxf(fmaxf(l0, l1), fmaxf(l2, l3));
    const float e0 = expf(l0 - m), e1 = expf(l1 - m), e2 = expf(l2 - m), e3 = expf(l3 - m);
    const float inv = 1.f / (e0 + e1 + e2 + e3);
    const float es[4] = {e0, e1, e2, e3};
    const float wj = es[j & 3] * inv;
    const float ox = tanhf(lgp[32 + 2 * j])     + ref[(size_t)gp * 2];
    const float oy = tanhf(lgp[32 + 2 * j + 1]) + ref[(size_t)gp * 2 + 1];
    const float sc = 0.5f * (float)(Wl - 1);
    samp4[(size_t)gp * 32 + j] = make_float4(wj, (ox + 1.f) * sc, (oy + 1.f) * sc, 0.f);
  }
}

// ---------------------------------------------------------------------------
// k3: 8 points/block (4096 blocks). Tap precompute (256 slots, 1/thread) ->
// fp16 gather: thread = (pt t>>5, head (t>>2)&7, dq t&3), 16 B half8 taps,
// fp32 accumulate, coalesced 32 B out writes.
// ---------------------------------------------------------------------------
__global__ __launch_bounds__(256) void k3_main(
    const _Float16* __restrict__ g16,
    const float4* __restrict__ samp4,
    const float* __restrict__ embed_b,   // (L, 32)
    float* __restrict__ out)             // (32768, 256)
{
  __shared__ int4   tofs[256];
  __shared__ float4 tws[256];
  const int t = threadIdx.x, blk = blockIdx.x;   // 4096 blocks
  const int gp0 = blk * 8;
  const int l = (gp0 >> 10) & 3, b = gp0 >> 12;
  const int Wl = 64 >> l;
  const int gbase = kGoff[l] + b * Wl * Wl * 32;  // half units

  {  // one tap slot per thread
    const float4 s = samp4[(size_t)gp0 * 32 + t];
    const float fx = s.y, fy = s.z;
    const float x0f = floorf(fx), y0f = floorf(fy);
    const int x0 = (int)x0f, y0 = (int)y0f, x1 = x0 + 1, y1 = y0 + 1;
    const float wx1 = fx - x0f, wy1 = fy - y0f;
    const float wx0 = 1.f - wx1, wy0 = 1.f - wy1;
    const float xv0 = (x0 >= 0 && x0 < Wl) ? 1.f : 0.f;
    const float xv1 = (x1 >= 0 && x1 < Wl) ? 1.f : 0.f;
    const float yv0 = (y0 >= 0 && y0 < Wl) ? 1.f : 0.f;
    const float yv1 = (y1 >= 0 && y1 < Wl) ? 1.f : 0.f;
    const int x0c = min(max(x0, 0), Wl - 1), x1c = min(max(x1, 0), Wl - 1);
    const int y0c = min(max(y0, 0), Wl - 1), y1c = min(max(y1, 0), Wl - 1);
    tofs[t] = make_int4(gbase + (y0c * Wl + x0c) * 32,
                        gbase + (y0c * Wl + x1c) * 32,
                        gbase + (y1c * Wl + x0c) * 32,
                        gbase + (y1c * Wl + x1c) * 32);
    const float w = s.x;
    tws[t] = make_float4(w * wy0 * wx0 * yv0 * xv0,
                         w * wy0 * wx1 * yv0 * xv1,
                         w * wy1 * wx0 * yv1 * xv0,
                         w * wy1 * wx1 * yv1 * xv1);
  }
  __syncthreads();

  const int dq = t & 3, h = (t >> 2) & 7, pt = t >> 5;
  float a[8];
  {
    const float4* bb = (const float4*)(embed_b + l * 32 + dq * 8);
    const float4 b0 = bb[0], b1 = bb[1];
    a[0] = b0.x; a[1] = b0.y; a[2] = b0.z; a[3] = b0.w;
    a[4] = b1.x; a[5] = b1.y; a[6] = b1.z; a[7] = b1.w;
  }
  #pragma unroll
  for (int s = 0; s < 4; ++s) {
    const int slot = pt * 32 + h * 4 + s;
    const int4   o = tofs[slot];
    const float4 w = tws[slot];
    const half8 v00 = *(const half8*)(g16 + o.x + dq * 8);
    const half8 v01 = *(const half8*)(g16 + o.y + dq * 8);
    const half8 v10 = *(const half8*)(g16 + o.z + dq * 8);
    const half8 v11 = *(const half8*)(g16 + o.w + dq * 8);
    #pragma unroll
    for (int j = 0; j < 8; ++j)
      a[j] += w.x * (float)v00[j] + w.y * (float)v01[j]
            + w.z * (float)v10[j] + w.w * (float)v11[j];
  }
  float* od = out + (size_t)(gp0 + pt) * 256 + h * 32 + dq * 8;
  ((float4*)od)[0] = make_float4(a[0], a[1], a[2], a[3]);
  ((float4*)od)[1] = make_float4(a[4], a[5], a[6], a[7]);
}

// ---------------------------------------------------------------------------
extern "C" void kernel_launch(void* const* d_in, const int* in_sizes, int n_in,
                              void* d_out, int out_size, void* d_ws, size_t ws_size,
                              hipStream_t stream) {
  const float* x      = (const float*)d_in[0];
  const float* ref    = (const float*)d_in[1];
  const float* w_attn = (const float*)d_in[6];
  const float* b_attn = (const float*)d_in[7];
  const float* w_off  = (const float*)d_in[8];
  const float* b_off  = (const float*)d_in[9];
  const float* emb_w  = (const float*)d_in[10];
  const float* emb_b  = (const float*)d_in[11];
  float* ws  = (float*)d_ws;
  float* out = (float*)d_out;

  _Float16* g16   = (_Float16*)(ws + G_F);
  float4*   samp4 = (float4*)(ws + SAMP_F);

  stage1<<<NG_GPROJ + B_ * L_ * P_ / 64, 256, 0, stream>>>(
      (const float*)d_in[2], (const float*)d_in[3],
      (const float*)d_in[4], (const float*)d_in[5], emb_w, g16,
      x, ref, w_attn, b_attn, w_off, b_off, samp4);

  k3_main<<<B_ * L_ * P_ / 8, 256, 0, stream>>>(g16, samp4, emb_b, out);
}